// Round 7
// baseline (534.584 us; speedup 1.0000x reference)
//
#include <hip/hip_runtime.h>

// B=4096, D=64, DM=256, K=32, KA=16, S=50
#define B_N 4096
#define SQUARINGS 7     // on G^2 => G^256 total

// ---- workspace layout (float offsets) ----
#define OFF_W5    0        // 5 x [64 k][256 m]: ZQ, LK, LV, CK, CV
#define OFF_B5    81920    // 5 x [256]: bq, bl, bvl, bc, bvc
#define OFF_KALL  83200    // [48][256]
#define OFF_VALL  95488    // [48][256]
#define OFF_M     107776   // [256][64]
#define OFF_G     124160   // [64][64]
#define OFF_AL    128256   // [64 zk][64 azk]  ZQ@LK^T
#define OFF_AC    132352   // [64][64]         ZQ@CK^T
#define OFF_LVM   136448   // [64 azk][64 d]   LV@M
#define OFF_CVM   140544   // [64][64]         CV@M
#define OFF_VM    144640   // [48 s][64 d]     VALL@M
#define OFF_R1    147712   // [64 zk][64]: cols 0..47 P=ZQ@KALL^T, 48..63 aanc
#define OFF_R2    151808   // [64 zk][64]: cols 0..31 chanc, 32 ul, 33 uc, rest 0
#define OFF_VL    155904   // [64] LK@bq
#define OFF_VC    155968   // [64] CK@bq
#define OFF_CS    156032   // [48] bq.KALL_s
#define OFF_AN2   156080   // [48] |anchor_s|^2
#define OFF_BVML  156128   // [64]
#define OFF_BVMC  156192   // [64]
#define OFF_CLC   156256   // [2]
#define OFF_A     156320   // [4096]
#define OFF_Bc    160416   // [4096]
#define OFF_LKT   164512   // [256 m][64 j] = LK^T
#define OFF_CKT   180896   // [256][64]
#define OFF_KALLT 197280   // [256 m][48 s]
#define OFF_G2    209568   // [64][64] = G@G
#define OFF_CNT1  213664   // uint: k1a done count
#define OFF_CNT2  213665   // uint: k2 main done count

// ---- k2 main LDS (floats) ----
#define C_CS    0
#define C_AN2   48
#define C_VL    96
#define C_VC    160
#define C_BVML  224
#define C_BVMC  288
#define C_FB    352
#define C_CLC   416
#define S_PART  424       // [4 b][6 v][4 w][64]
#define S_REDV  6568      // [4 b][4 v][64]
#define S_SCL   7592      // [4 b][16]
#define S_WSW   7656      // [4 b][48]
#define S_GP    7848      // [4 b][4 w][64]
#define SMEM_K2 8872
// ---- sigma LDS (same buffer) ----
#define SG_BUF0 0
#define SG_BUF1 4096
#define SG_TR   8192      // [2][4] trace partials
#define SG_V    8200      // [64]
#define SG_RS   8264
#define SG_SC0  8265

__device__ __forceinline__ float rlane(float v, int l) {
  return __int_as_float(__builtin_amdgcn_readlane(__float_as_int(v), l));
}

// ===================== K1: all folds, 2438 blocks (2004 stage1 + 434 stage2) =====================
__global__ __launch_bounds__(256)
void k1_all(const float* __restrict__ chart_emb, const float* __restrict__ a_chart_emb,
            const float* __restrict__ zW, const float* __restrict__ zb,
            const float* __restrict__ latW, const float* __restrict__ latb,
            const float* __restrict__ codeW, const float* __restrict__ codeb,
            const float* __restrict__ Wq, const float* __restrict__ Wk,
            const float* __restrict__ Wv, const float* __restrict__ Wo,
            const float* __restrict__ fW, const float* __restrict__ chanc,
            const float* __restrict__ aanc, float* __restrict__ ws) {
  __shared__ float red[256];
  const int t = threadIdx.x;
  const int b = blockIdx.x;
  unsigned* cnt1 = (unsigned*)(ws + OFF_CNT1);

  if (b < 2004) {
    // ---------------- stage 1 ----------------
    const float* Arow; const float* Bm;
    int astride = 1, bstride = 256, jbase = 0, dstBase;
    int tposeKind = 0, tRow = 0;   // 1: LKT, 2: CKT, 3: KALLT
    if (b < 1300) {
      int u = b / 260, r = b - u * 260;
      int i = r >> 2, jc = r & 3; jbase = jc * 64;
      const float* Amat = (u == 0) ? zW : (u <= 2 ? latW : codeW);
      const float* bias = (u == 0) ? zb : (u <= 2 ? latb : codeb);
      Bm = (u == 0) ? Wq : ((u == 1 || u == 3) ? Wk : Wv);
      if (i < 64) {
        Arow = Amat + i * 256; dstBase = OFF_W5 + u * 16384 + i * 256 + jbase;
        if (u == 1) { tposeKind = 1; tRow = i; }
        if (u == 3) { tposeKind = 2; tRow = i; }
      } else {
        Arow = bias; dstBase = OFF_B5 + u * 256 + jbase;
      }
    } else if (b < 1684) {
      int rr = b - 1300; int row = rr >> 2, jc = rr & 3; jbase = jc * 64;
      int s = (row < 48) ? row : row - 48;
      Bm = (row < 48) ? Wk : Wv;
      Arow = (s < 16) ? (a_chart_emb + s * 256) : (chart_emb + (s - 16) * 256);
      dstBase = OFF_KALL + row * 256 + jbase;
      if (row < 48) { tposeKind = 3; tRow = row; }
    } else if (b < 1940) {
      int i = b - 1684;
      Arow = Wo + i * 256; Bm = fW; bstride = 64;
      dstBase = OFF_M + i * 64;
    } else {
      int i = b - 1940;
      Arow = fW + i; astride = 64; Bm = fW; bstride = 64;
      dstBase = OFF_G + i * 64;
    }

    const int j = t & 63, ks = t >> 6;
    const float* ap = Arow + (ks * 64) * astride;
    const float* bp = Bm + (ks * 64) * bstride + jbase + j;
    float a0 = 0.f, a1 = 0.f, a2 = 0.f, a3 = 0.f;
    #pragma unroll 4
    for (int k = 0; k < 64; k += 4) {
      a0 += ap[(k + 0) * astride] * bp[(k + 0) * bstride];
      a1 += ap[(k + 1) * astride] * bp[(k + 1) * bstride];
      a2 += ap[(k + 2) * astride] * bp[(k + 2) * bstride];
      a3 += ap[(k + 3) * astride] * bp[(k + 3) * bstride];
    }
    red[t] = (a0 + a1) + (a2 + a3);
    __syncthreads();
    if (t < 64) {
      float v = red[t] + red[64 + t] + red[128 + t] + red[192 + t];
      ws[dstBase + t] = v;
      if (tposeKind == 1)      ws[OFF_LKT  + (jbase + t) * 64 + tRow] = v;
      else if (tposeKind == 2) ws[OFF_CKT  + (jbase + t) * 64 + tRow] = v;
      else if (tposeKind == 3) ws[OFF_KALLT + (jbase + t) * 48 + tRow] = v;
    }
    __threadfence();
    __syncthreads();
    if (t == 0) atomicAdd(cnt1, 1u);
    return;
  }

  // ---------------- stage 2: wait for stage 1 ----------------
  if (t == 0) {
    while (atomicAdd(cnt1, 0u) < 2004u) __builtin_amdgcn_s_sleep(2);
  }
  __syncthreads();
  __threadfence();

  const int b2 = b - 2004;
  const float* ZQ = ws + OFF_W5;
  const float* LK = ws + OFF_W5 + 16384;
  const float* LV = ws + OFF_W5 + 32768;
  const float* CK = ws + OFF_W5 + 49152;
  const float* CV = ws + OFF_W5 + 65536;
  const float* Mm = ws + OFF_M;
  const float* Gm = ws + OFF_G;
  const float* KAp = ws + OFF_KALL;
  const float* VAp = ws + OFF_VALL;
  const float* bq = ws + OFF_B5;
  const float* bl = ws + OFF_B5 + 256;
  const float* bvl = ws + OFF_B5 + 512;
  const float* bc = ws + OFF_B5 + 768;
  const float* bvc = ws + OFF_B5 + 1024;

  if (b2 == 432) {
    for (int e = t; e < 1024; e += 256) {
      int s = e >> 6, k = e & 63;
      ws[OFF_R1 + k * 64 + 48 + s] = aanc[s * 64 + k];
    }
    for (int e = t; e < 2048; e += 256) {
      int s = e >> 6, k = e & 63;
      ws[OFF_R2 + k * 64 + s] = chanc[s * 64 + k];
    }
    for (int e = t; e < 2048; e += 256) {
      int k = e >> 5, c = 32 + (e & 31);
      if (c >= 34) ws[OFF_R2 + k * 64 + c] = 0.f;
    }
    int r = t & 63;
    const float* arow; const float* vec;
    if (t < 64)       { arow = ZQ + r * 256; vec = bl; }
    else if (t < 128) { arow = ZQ + r * 256; vec = bc; }
    else if (t < 192) { arow = LK + r * 256; vec = bq; }
    else              { arow = CK + r * 256; vec = bq; }
    float a0 = 0.f, a1 = 0.f, a2 = 0.f, a3 = 0.f;
    #pragma unroll 4
    for (int m = 0; m < 256; m += 4) {
      a0 += arow[m] * vec[m];         a1 += arow[m + 1] * vec[m + 1];
      a2 += arow[m + 2] * vec[m + 2]; a3 += arow[m + 3] * vec[m + 3];
    }
    float s = (a0 + a1) + (a2 + a3);
    if (t < 64)       ws[OFF_R2 + r * 64 + 32] = s;
    else if (t < 128) ws[OFF_R2 + r * 64 + 33] = s;
    else if (t < 192) ws[OFF_VL + r] = s;
    else              ws[OFF_VC + r] = s;
    return;
  }
  if (b2 == 433) {
    if (t < 48) {
      const float* krow = KAp + t * 256;
      float s = 0.f;
      #pragma unroll 4
      for (int m = 0; m < 256; ++m) s += bq[m] * krow[m];
      ws[OFF_CS + t] = s;
    } else if (t < 96) {
      int s_ = t - 48;
      const float* anc = (s_ < 16) ? (aanc + s_ * 64) : (chanc + (s_ - 16) * 64);
      float s = 0.f;
      #pragma unroll 4
      for (int k = 0; k < 64; ++k) s += anc[k] * anc[k];
      ws[OFF_AN2 + s_] = s;
    } else if (t < 160) {
      int d = t - 96;
      float s = 0.f;
      #pragma unroll 4
      for (int m = 0; m < 256; ++m) s += bvl[m] * Mm[m * 64 + d];
      ws[OFF_BVML + d] = s;
    } else if (t < 224) {
      int d = t - 160;
      float s = 0.f;
      #pragma unroll 4
      for (int m = 0; m < 256; ++m) s += bvc[m] * Mm[m * 64 + d];
      ws[OFF_BVMC + d] = s;
    } else if (t == 224) {
      float s = 0.f;
      for (int m = 0; m < 256; ++m) s += bq[m] * bl[m];
      ws[OFF_CLC] = s;
    } else if (t == 225) {
      float s = 0.f;
      for (int m = 0; m < 256; ++m) s += bq[m] * bc[m];
      ws[OFF_CLC + 1] = s;
    }
    return;
  }

  // generic coalesced dot blocks (all B accessed row-major, lanes consecutive)
  const float* ap; const float* bp; int bs = 64, outBase, cnt = 64, len = 256;
  if (b2 < 64)        { ap = ZQ + b2 * 256;              bp = ws + OFF_LKT;   outBase = OFF_AL + b2 * 64; }
  else if (b2 < 128)  { int k = b2 - 64;  ap = ZQ + k * 256;  bp = ws + OFF_CKT; outBase = OFF_AC + k * 64; }
  else if (b2 < 192)  { int k = b2 - 128; ap = LV + k * 256;  bp = Mm;           outBase = OFF_LVM + k * 64; }
  else if (b2 < 256)  { int k = b2 - 192; ap = CV + k * 256;  bp = Mm;           outBase = OFF_CVM + k * 64; }
  else if (b2 < 304)  { int s = b2 - 256; ap = VAp + s * 256; bp = Mm;           outBase = OFF_VM + s * 64; }
  else if (b2 < 368)  { int k = b2 - 304; ap = ZQ + k * 256;  bp = ws + OFF_KALLT; bs = 48; outBase = OFF_R1 + k * 64; cnt = 48; }
  else                { int i = b2 - 368; ap = Gm + i * 64;   bp = Gm;           outBase = OFF_G2 + i * 64; len = 64; }

  const int j = t & 63, ks = t >> 6;
  const int sl = len >> 2;
  const float* app = ap + ks * sl;
  const float* bpp = bp + (ks * sl) * bs + j;
  float a0 = 0.f, a1 = 0.f, a2 = 0.f, a3 = 0.f;
  #pragma unroll 4
  for (int m = 0; m < sl; m += 4) {
    a0 += app[m] * bpp[m * bs];
    a1 += app[m + 1] * bpp[(m + 1) * bs];
    a2 += app[m + 2] * bpp[(m + 2) * bs];
    a3 += app[m + 3] * bpp[(m + 3) * bs];
  }
  red[t] = (a0 + a1) + (a2 + a3);
  __syncthreads();
  if (t < cnt) ws[outBase + t] = red[t] + red[64 + t] + red[128 + t] + red[192 + t];
}

// ===================== K2: main blocks + sigma/output block =====================
__global__ __launch_bounds__(256, 3)
void k2_main(const float* __restrict__ z, const float* __restrict__ rw,
             const float* __restrict__ az, const float* __restrict__ arw,
             const float* __restrict__ acz, const float* __restrict__ ctrl,
             const float* __restrict__ ecov, const float* __restrict__ fb,
             float* __restrict__ ws, float* __restrict__ out) {
  __shared__ __align__(16) float sm[SMEM_K2];
  const int t = threadIdx.x;
  const int wv = t >> 6, ln = t & 63;
  unsigned* cnt2 = (unsigned*)(ws + OFF_CNT2);

  if (blockIdx.x == 1024) {
    // ---------- sigma in registers: H symmetric, lane j holds column j ----------
    {
      float tv = (t < 64) ? ws[OFF_G2 + t * 65] : 0.f;
      #pragma unroll
      for (int m = 32; m >= 1; m >>= 1) tv += __shfl_xor(tv, m, 64);
      if (t == 0) sm[SG_SC0] = (tv > 0.f) ? 1.f / tv : 1.f;
    }
    __syncthreads();
    float colA[64];
    {
      float s0 = sm[SG_SC0];
      #pragma unroll
      for (int k = 0; k < 64; ++k) colA[k] = ws[OFF_G2 + k * 64 + ln] * s0;
    }
    for (int it = 0; it < SQUARINGS; ++it) {
      float cnew[16];
      #pragma unroll
      for (int r = 0; r < 16; ++r) {
        const int i = wv * 16 + r;     // wave-uniform row
        float a0 = 0.f, a1 = 0.f;
        #pragma unroll
        for (int k = 0; k < 64; k += 2) {
          a0 = fmaf(rlane(colA[k], i),     colA[k],     a0);
          a1 = fmaf(rlane(colA[k + 1], i), colA[k + 1], a1);
        }
        cnew[r] = a0 + a1;
      }
      float* buf = sm + ((it & 1) ? SG_BUF1 : SG_BUF0);
      #pragma unroll
      for (int r = 0; r < 16; ++r) buf[(wv * 16 + r) * 64 + ln] = cnew[r];
      float tp = 0.f;
      #pragma unroll
      for (int r = 0; r < 16; ++r) tp += rlane(cnew[r], wv * 16 + r);
      if (ln == 0) sm[SG_TR + (it & 1) * 4 + wv] = tp;
      __syncthreads();
      float tr = sm[SG_TR + (it & 1) * 4 + 0] + sm[SG_TR + (it & 1) * 4 + 1]
               + sm[SG_TR + (it & 1) * 4 + 2] + sm[SG_TR + (it & 1) * 4 + 3];
      float scl = (tr > 0.f) ? 1.f / tr : 1.f;
      #pragma unroll
      for (int k = 0; k < 64; ++k) colA[k] = buf[k * 64 + ln] * scl;
      // single barrier per iter: next iter writes the OTHER buffer
    }
    // max-norm column pick (every wave computes identically)
    float cn = 0.f;
    #pragma unroll
    for (int k = 0; k < 64; ++k) cn = fmaf(colA[k], colA[k], cn);
    float bv = cn; int bj = ln;
    #pragma unroll
    for (int m = 32; m >= 1; m >>= 1) {
      float ov = __shfl_xor(bv, m, 64);
      int   oj = __shfl_xor(bj, m, 64);
      if (ov > bv || (ov == bv && oj < bj)) { bv = ov; bj = oj; }
    }
    if (ln == bj && wv == 0) {
      #pragma unroll
      for (int k = 0; k < 64; ++k) sm[SG_V + k] = colA[k];
    }
    __syncthreads();
    if (t < 64) {                 // Rayleigh vs fp32 G (G symmetric -> coalesced column reads)
      float vv = sm[SG_V + ln];
      float y = 0.f;
      #pragma unroll
      for (int k = 0; k < 64; ++k) y = fmaf(ws[OFF_G + k * 64 + ln], rlane(vv, k), y);
      float num = vv * y, den = vv * vv;
      #pragma unroll
      for (int m = 32; m >= 1; m >>= 1) {
        num += __shfl_xor(num, m, 64);
        den += __shfl_xor(den, m, 64);
      }
      if (t == 0) {
        float lam = (den > 1e-37f) ? num / den : 0.f;
        lam = fmaxf(lam, 0.f);
        float sg = sqrtf(lam);
        sm[SG_RS] = 1.f / fmaxf(sg, 1e-8f);
      }
    }
    __syncthreads();
    float rs = sm[SG_RS];
    // ---------- wait for main blocks, then produce output ----------
    if (t == 0) {
      while (atomicAdd(cnt2, 0u) < 1024u) __builtin_amdgcn_s_sleep(2);
    }
    __syncthreads();
    __threadfence();
    for (int i = t; i < B_N; i += 256)
      out[i] = fmaf(ws[OFF_A + i], rs, ws[OFF_Bc + i]);
    return;
  }

  // ---- stage consts into LDS ----
  for (int e = t; e < 418; e += 256) {
    float v;
    if (e < 48)       v = ws[OFF_CS + e];
    else if (e < 96)  v = ws[OFF_AN2 + e - 48];
    else if (e < 160) v = ws[OFF_VL + e - 96];
    else if (e < 224) v = ws[OFF_VC + e - 160];
    else if (e < 288) v = ws[OFF_BVML + e - 224];
    else if (e < 352) v = ws[OFF_BVMC + e - 288];
    else if (e < 416) v = fb[e - 352];
    else              v = ws[OFF_CLC + e - 416];
    sm[e] = v;
  }

  // ---- folded weights into registers (k-slice 16 per wave, lane = output col) ----
  float aLr[16], aCr[16], lvr[16], cvr[16], rAr[16], rBr[16], vmr[12];
  {
    const int kb = wv << 4;
    #pragma unroll
    for (int kk = 0; kk < 16; ++kk) {
      const int k = kb + kk;
      aLr[kk] = ws[OFF_AL  + k * 64 + ln];
      aCr[kk] = ws[OFF_AC  + k * 64 + ln];
      lvr[kk] = ws[OFF_LVM + k * 64 + ln];
      cvr[kk] = ws[OFF_CVM + k * 64 + ln];
      rAr[kk] = ws[OFF_R1  + k * 64 + ln];
      rBr[kk] = ws[OFF_R2  + k * 64 + ln];
    }
    #pragma unroll
    for (int ss = 0; ss < 12; ++ss) vmr[ss] = ws[OFF_VM + (wv * 12 + ss) * 64 + ln];
  }

  const int b0 = blockIdx.x * 4;

  // ---- phase 1: bilinear partials ----
  #pragma unroll
  for (int bi = 0; bi < 4; ++bi) {
    const int gb = b0 + bi;
    const float vz = z[gb * 64 + ln];
    const float va = az[gb * 64 + ln];
    const float vq = acz[gb * 64 + ln];
    float t1 = 0.f, t2 = 0.f, t3 = 0.f, t4 = 0.f, r1 = 0.f, r2 = 0.f;
    #pragma unroll
    for (int kk = 0; kk < 16; ++kk) {
      const int ksrc = (wv << 4) + kk;
      float sz = rlane(vz, ksrc);
      float sa = rlane(va, ksrc);
      float sq = rlane(vq, ksrc);
      t1 = fmaf(sz, aLr[kk], t1);
      t2 = fmaf(sz, aCr[kk], t2);
      r1 = fmaf(sz, rAr[kk], r1);
      r2 = fmaf(sz, rBr[kk], r2);
      t3 = fmaf(sa, lvr[kk], t3);
      t4 = fmaf(sq, cvr[kk], t4);
    }
    const int pb = S_PART + ((bi * 6) * 4 + wv) * 64 + ln;
    sm[pb]        = t1;
    sm[pb + 256]  = t2;
    sm[pb + 512]  = t3;
    sm[pb + 768]  = t4;
    sm[pb + 1024] = r1;
    sm[pb + 1280] = r2;
    if (bi == wv) {
      float zn = vz * vz;
      float dl = (vz - va) * (vz - va);
      float dq = (vz - vq) * (vz - vq);
      #pragma unroll
      for (int m = 32; m >= 1; m >>= 1) {
        zn += __shfl_xor(zn, m, 64);
        dl += __shfl_xor(dl, m, 64);
        dq += __shfl_xor(dq, m, 64);
      }
      if (ln == 0) {
        sm[S_SCL + bi * 16 + 2] = zn;
        sm[S_SCL + bi * 16 + 3] = dl;
        sm[S_SCL + bi * 16 + 4] = dq;
      }
    }
  }
  __syncthreads();

  // ---- phase 2: cross-wave reduce ----
  for (int tid = wv; tid < 24; tid += 4) {
    const int b = tid / 6, v = tid % 6;
    const int pb = S_PART + ((b * 6 + v) * 4) * 64 + ln;
    float s0 = sm[pb] + sm[pb + 64] + sm[pb + 128] + sm[pb + 192];
    if (v < 2) {
      const float xv = (v == 0) ? az[(b0 + b) * 64 + ln] : acz[(b0 + b) * 64 + ln];
      float d1 = s0 * xv;
      float d2 = xv * sm[((v == 0) ? C_VL : C_VC) + ln];
      #pragma unroll
      for (int m = 32; m >= 1; m >>= 1) {
        d1 += __shfl_xor(d1, m, 64);
        d2 += __shfl_xor(d2, m, 64);
      }
      if (ln == 0) {
        sm[S_SCL + b * 16 + v]     = d1;
        sm[S_SCL + b * 16 + 5 + v] = d2;
      }
    } else {
      sm[S_REDV + (b * 4 + (v - 2)) * 64 + ln] = s0;
    }
  }
  __syncthreads();

  // ---- phase 3: scores + softmax (wave wv -> batch wv) ----
  {
    const int b = wv, gb = b0 + b;
    float rwv = 1.f;
    if (ln < 16)      rwv = arw[gb * 16 + ln];
    else if (ln < 48) rwv = rw[gb * 32 + (ln - 16)];
    float sc_;
    if (ln < 48) {
      float qk = sm[S_REDV + (b * 4 + 2) * 64 + ln] + sm[C_CS + ln];
      float za = (ln < 16) ? sm[S_REDV + (b * 4 + 2) * 64 + 48 + ln]
                           : sm[S_REDV + (b * 4 + 3) * 64 + (ln - 16)];
      float d2 = sm[S_SCL + b * 16 + 2] - 2.f * za + sm[C_AN2 + ln];
      sc_ = rwv * qk * 0.0625f - d2;
    } else if (ln == 48) {
      sc_ = (sm[S_SCL + b * 16 + 0] + sm[S_REDV + (b * 4 + 3) * 64 + 32]
             + sm[S_SCL + b * 16 + 5] + sm[C_CLC]) * 0.0625f - sm[S_SCL + b * 16 + 3];
    } else if (ln == 49) {
      sc_ = (sm[S_SCL + b * 16 + 1] + sm[S_REDV + (b * 4 + 3) * 64 + 33]
             + sm[S_SCL + b * 16 + 6] + sm[C_CLC + 1]) * 0.0625f - sm[S_SCL + b * 16 + 4];
    } else sc_ = -3.0e30f;
    float mx = sc_;
    #pragma unroll
    for (int m = 32; m >= 1; m >>= 1) mx = fmaxf(mx, __shfl_xor(mx, m, 64));
    float ex = (ln < 50) ? __expf(sc_ - mx) : 0.f;
    float sum = ex;
    #pragma unroll
    for (int m = 32; m >= 1; m >>= 1) sum += __shfl_xor(sum, m, 64);
    float wgt = ex / sum;
    if (ln < 48)       sm[S_WSW + b * 48 + ln] = wgt * rwv;
    else if (ln == 48) sm[S_SCL + b * 16 + 7] = wgt;
    else if (ln == 49) sm[S_SCL + b * 16 + 8] = wgt;
  }
  __syncthreads();

  // ---- phase 4: VM partial ----
  #pragma unroll
  for (int bi = 0; bi < 4; ++bi) {
    float gp = 0.f;
    #pragma unroll
    for (int ss = 0; ss < 12; ++ss)
      gp = fmaf(sm[S_WSW + bi * 48 + wv * 12 + ss], vmr[ss], gp);
    sm[S_GP + (bi * 4 + wv) * 64 + ln] = gp;
  }
  __syncthreads();

  // ---- phase 5: assemble g, projection epilogue ----
  {
    const int b = wv, gb = b0 + b;
    const int gp0 = S_GP + (b * 4) * 64 + ln;
    float g = sm[gp0] + sm[gp0 + 64] + sm[gp0 + 128] + sm[gp0 + 192];
    float wL = sm[S_SCL + b * 16 + 7], wC = sm[S_SCL + b * 16 + 8];
    g = fmaf(wL, sm[S_REDV + (b * 4 + 0) * 64 + ln] + sm[C_BVML + ln], g);
    g = fmaf(wC, sm[S_REDV + (b * 4 + 1) * 64 + ln] + sm[C_BVMC + ln], g);
    float c = ctrl[gb * 64 + ln];
    float e = ecov[gb * 64 + ln];
    float fbv = sm[C_FB + ln];
    float gc = g * c, ge = g * e, ec = e * c, ee = e * e, fc = fbv * c, fe = fbv * e;
    #pragma unroll
    for (int m = 32; m >= 1; m >>= 1) {
      gc += __shfl_xor(gc, m, 64);
      ge += __shfl_xor(ge, m, 64);
      ec += __shfl_xor(ec, m, 64);
      ee += __shfl_xor(ee, m, 64);
      fc += __shfl_xor(fc, m, 64);
      fe += __shfl_xor(fe, m, 64);
    }
    if (ln == 0) {
      float A, Bv;
      if (ee > 1e-8f) { float r = ec / ee; A = gc - ge * r; Bv = fc - fe * r; }
      else { A = gc; Bv = fc; }
      ws[OFF_A  + gb] = A;
      ws[OFF_Bc + gb] = Bv;
    }
  }
  __threadfence();
  __syncthreads();
  if (t == 0) atomicAdd(cnt2, 1u);
}

extern "C" void kernel_launch(void* const* d_in, const int* in_sizes, int n_in,
                              void* d_out, int out_size, void* d_ws, size_t ws_size,
                              hipStream_t stream) {
  const float* z     = (const float*)d_in[0];
  const float* rw    = (const float*)d_in[1];
  const float* az    = (const float*)d_in[2];
  const float* arw   = (const float*)d_in[3];
  const float* acz   = (const float*)d_in[4];
  const float* ctrl  = (const float*)d_in[5];
  const float* ecov  = (const float*)d_in[6];
  const float* chemb = (const float*)d_in[7];
  const float* chanc = (const float*)d_in[8];
  const float* aemb  = (const float*)d_in[9];
  const float* aanc  = (const float*)d_in[10];
  const float* zW    = (const float*)d_in[11];
  const float* zb    = (const float*)d_in[12];
  const float* latW  = (const float*)d_in[13];
  const float* latb  = (const float*)d_in[14];
  const float* codeW = (const float*)d_in[15];
  const float* codeb = (const float*)d_in[16];
  const float* Wq    = (const float*)d_in[17];
  const float* Wk    = (const float*)d_in[18];
  const float* Wv    = (const float*)d_in[19];
  const float* Wo    = (const float*)d_in[20];
  const float* fW    = (const float*)d_in[21];
  const float* fb    = (const float*)d_in[22];
  float* ws  = (float*)d_ws;
  float* out = (float*)d_out;

  hipMemsetAsync((char*)d_ws + OFF_CNT1 * sizeof(float), 0, 8, stream);
  k1_all<<<2438, 256, 0, stream>>>(chemb, aemb, zW, zb, latW, latb, codeW, codeb,
                                   Wq, Wk, Wv, Wo, fW, chanc, aanc, ws);
  k2_main<<<1025, 256, 0, stream>>>(z, rw, az, arw, acz, ctrl, ecov, fb, ws, out);
}

// Round 8
// 215.002 us; speedup vs baseline: 2.4864x; 2.4864x over previous
//
#include <hip/hip_runtime.h>

// B=4096, D=64, DM=256, K=32, KA=16, S=50
#define B_N 4096
#define SQUARINGS 7     // applied to G^2  => G^256 total

// ---- workspace layout (float offsets) ----
#define OFF_W5    0        // 5 x [64 k][256 m]: ZQ, LK, LV, CK, CV
#define OFF_B5    81920    // 5 x [256]: bq, bl, bvl, bc, bvc
#define OFF_KALL  83200    // [48][256]
#define OFF_VALL  95488    // [48][256]
#define OFF_M     107776   // [256][64]
#define OFF_G     124160   // [64][64]
#define OFF_AL    128256   // [64 zk][64 azk]  ZQ@LK^T
#define OFF_AC    132352   // [64][64]         ZQ@CK^T
#define OFF_LVM   136448   // [64 azk][64 d]   LV@M
#define OFF_CVM   140544   // [64][64]         CV@M
#define OFF_VM    144640   // [48 s][64 d]     VALL@M
#define OFF_R1    147712   // [64 zk][64]: cols 0..47 P=ZQ@KALL^T, 48..63 aanc
#define OFF_R2    151808   // [64 zk][64]: cols 0..31 chanc, 32 ul, 33 uc, rest 0
#define OFF_VL    155904   // [64] LK@bq
#define OFF_VC    155968   // [64] CK@bq
#define OFF_CS    156032   // [48] bq.KALL_s
#define OFF_AN2   156080   // [48] |anchor_s|^2
#define OFF_BVML  156128   // [64]
#define OFF_BVMC  156192   // [64]
#define OFF_CLC   156256   // [2]
#define OFF_RS    156288   // 1/sigma
#define OFF_A     156320   // [4096]
#define OFF_Bc    160416   // [4096]
#define OFF_LKT   164512   // [256 m][64 j] = LK^T
#define OFF_CKT   180896   // [256][64]
#define OFF_KALLT 197280   // [256 m][48 s]
#define OFF_G2    209568   // [64][64] = G@G

// ---- k2 main LDS (floats) ----
#define C_CS    0
#define C_AN2   48
#define C_VL    96
#define C_VC    160
#define C_BVML  224
#define C_BVMC  288
#define C_FB    352
#define C_CLC   416
#define S_PART  424       // [4 b][6 v][4 w][64]
#define S_REDV  6568      // [4 b][4 v][64]
#define S_SCL   7592      // [4 b][16]
#define S_WSW   7656      // [4 b][48]
#define S_GP    7848      // [4 b][4 w][64]
#define SMEM_K2 8872
// ---- sigma LDS (same buffer) ----
#define SG_BUF0 0
#define SG_BUF1 4096
#define SG_TR   8192      // [2][4] trace partials
#define SG_V    8200      // [64]
#define SG_SC0  8265

__device__ __forceinline__ float rlane(float v, int l) {
  return __int_as_float(__builtin_amdgcn_readlane(__float_as_int(v), l));
}

// ===================== K1a: stage-1 folds, 2004 blocks =====================
__global__ __launch_bounds__(256)
void k1a_fold(const float* __restrict__ chart_emb, const float* __restrict__ a_chart_emb,
              const float* __restrict__ zW, const float* __restrict__ zb,
              const float* __restrict__ latW, const float* __restrict__ latb,
              const float* __restrict__ codeW, const float* __restrict__ codeb,
              const float* __restrict__ Wq, const float* __restrict__ Wk,
              const float* __restrict__ Wv, const float* __restrict__ Wo,
              const float* __restrict__ fW, float* __restrict__ ws) {
  __shared__ float red[256];
  const int t = threadIdx.x;
  const int b = blockIdx.x;

  const float* Arow; const float* Bm;
  int astride = 1, bstride = 256, jbase = 0, dstBase;
  int tposeKind = 0, tRow = 0;   // 1: LKT, 2: CKT, 3: KALLT
  if (b < 1300) {
    int u = b / 260, r = b - u * 260;
    int i = r >> 2, jc = r & 3; jbase = jc * 64;
    const float* Amat = (u == 0) ? zW : (u <= 2 ? latW : codeW);
    const float* bias = (u == 0) ? zb : (u <= 2 ? latb : codeb);
    Bm = (u == 0) ? Wq : ((u == 1 || u == 3) ? Wk : Wv);
    if (i < 64) {
      Arow = Amat + i * 256; dstBase = OFF_W5 + u * 16384 + i * 256 + jbase;
      if (u == 1) { tposeKind = 1; tRow = i; }
      if (u == 3) { tposeKind = 2; tRow = i; }
    } else {
      Arow = bias; dstBase = OFF_B5 + u * 256 + jbase;
    }
  } else if (b < 1684) {
    int rr = b - 1300; int row = rr >> 2, jc = rr & 3; jbase = jc * 64;
    int s = (row < 48) ? row : row - 48;
    Bm = (row < 48) ? Wk : Wv;
    Arow = (s < 16) ? (a_chart_emb + s * 256) : (chart_emb + (s - 16) * 256);
    dstBase = OFF_KALL + row * 256 + jbase;
    if (row < 48) { tposeKind = 3; tRow = row; }
  } else if (b < 1940) {
    int i = b - 1684;
    Arow = Wo + i * 256; Bm = fW; bstride = 64;
    dstBase = OFF_M + i * 64;
  } else {
    int i = b - 1940;
    Arow = fW + i; astride = 64; Bm = fW; bstride = 64;
    dstBase = OFF_G + i * 64;
  }

  const int j = t & 63, ks = t >> 6;
  const float* ap = Arow + (ks * 64) * astride;
  const float* bp = Bm + (ks * 64) * bstride + jbase + j;
  float a0 = 0.f, a1 = 0.f, a2 = 0.f, a3 = 0.f;
  #pragma unroll 4
  for (int k = 0; k < 64; k += 4) {
    a0 += ap[(k + 0) * astride] * bp[(k + 0) * bstride];
    a1 += ap[(k + 1) * astride] * bp[(k + 1) * bstride];
    a2 += ap[(k + 2) * astride] * bp[(k + 2) * bstride];
    a3 += ap[(k + 3) * astride] * bp[(k + 3) * bstride];
  }
  red[t] = (a0 + a1) + (a2 + a3);
  __syncthreads();
  if (t < 64) {
    float v = red[t] + red[64 + t] + red[128 + t] + red[192 + t];
    ws[dstBase + t] = v;
    if (tposeKind == 1)      ws[OFF_LKT   + (jbase + t) * 64 + tRow] = v;
    else if (tposeKind == 2) ws[OFF_CKT   + (jbase + t) * 64 + tRow] = v;
    else if (tposeKind == 3) ws[OFF_KALLT + (jbase + t) * 48 + tRow] = v;
  }
}

// ===================== K1b: stage-2 folds, 434 blocks =====================
__global__ __launch_bounds__(256)
void k1b_fold(const float* __restrict__ chanc, const float* __restrict__ aanc,
              float* __restrict__ ws) {
  __shared__ float red[256];
  const int t = threadIdx.x;
  const int b2 = blockIdx.x;
  const float* ZQ = ws + OFF_W5;
  const float* LK = ws + OFF_W5 + 16384;
  const float* LV = ws + OFF_W5 + 32768;
  const float* CK = ws + OFF_W5 + 49152;
  const float* CV = ws + OFF_W5 + 65536;
  const float* Mm = ws + OFF_M;
  const float* Gm = ws + OFF_G;
  const float* VAp = ws + OFF_VALL;
  const float* KAp = ws + OFF_KALL;
  const float* bq = ws + OFF_B5;
  const float* bl = ws + OFF_B5 + 256;
  const float* bvl = ws + OFF_B5 + 512;
  const float* bc = ws + OFF_B5 + 768;
  const float* bvc = ws + OFF_B5 + 1024;

  if (b2 == 432) {
    for (int e = t; e < 1024; e += 256) {
      int s = e >> 6, k = e & 63;
      ws[OFF_R1 + k * 64 + 48 + s] = aanc[s * 64 + k];
    }
    for (int e = t; e < 2048; e += 256) {
      int s = e >> 6, k = e & 63;
      ws[OFF_R2 + k * 64 + s] = chanc[s * 64 + k];
    }
    for (int e = t; e < 2048; e += 256) {
      int k = e >> 5, c = 32 + (e & 31);
      if (c >= 34) ws[OFF_R2 + k * 64 + c] = 0.f;
    }
    int r = t & 63;
    const float* arow; const float* vec;
    if (t < 64)       { arow = ZQ + r * 256; vec = bl; }
    else if (t < 128) { arow = ZQ + r * 256; vec = bc; }
    else if (t < 192) { arow = LK + r * 256; vec = bq; }
    else              { arow = CK + r * 256; vec = bq; }
    float a0 = 0.f, a1 = 0.f, a2 = 0.f, a3 = 0.f;
    #pragma unroll 4
    for (int m = 0; m < 256; m += 4) {
      a0 += arow[m] * vec[m];         a1 += arow[m + 1] * vec[m + 1];
      a2 += arow[m + 2] * vec[m + 2]; a3 += arow[m + 3] * vec[m + 3];
    }
    float s = (a0 + a1) + (a2 + a3);
    if (t < 64)       ws[OFF_R2 + r * 64 + 32] = s;
    else if (t < 128) ws[OFF_R2 + r * 64 + 33] = s;
    else if (t < 192) ws[OFF_VL + r] = s;
    else              ws[OFF_VC + r] = s;
    return;
  }
  if (b2 == 433) {
    if (t < 48) {
      const float* krow = KAp + t * 256;
      float s = 0.f;
      #pragma unroll 4
      for (int m = 0; m < 256; ++m) s += bq[m] * krow[m];
      ws[OFF_CS + t] = s;
    } else if (t < 96) {
      int s_ = t - 48;
      const float* anc = (s_ < 16) ? (aanc + s_ * 64) : (chanc + (s_ - 16) * 64);
      float s = 0.f;
      #pragma unroll 4
      for (int k = 0; k < 64; ++k) s += anc[k] * anc[k];
      ws[OFF_AN2 + s_] = s;
    } else if (t < 160) {
      int d = t - 96;
      float s = 0.f;
      #pragma unroll 4
      for (int m = 0; m < 256; ++m) s += bvl[m] * Mm[m * 64 + d];
      ws[OFF_BVML + d] = s;
    } else if (t < 224) {
      int d = t - 160;
      float s = 0.f;
      #pragma unroll 4
      for (int m = 0; m < 256; ++m) s += bvc[m] * Mm[m * 64 + d];
      ws[OFF_BVMC + d] = s;
    } else if (t == 224) {
      float s = 0.f;
      for (int m = 0; m < 256; ++m) s += bq[m] * bl[m];
      ws[OFF_CLC] = s;
    } else if (t == 225) {
      float s = 0.f;
      for (int m = 0; m < 256; ++m) s += bq[m] * bc[m];
      ws[OFF_CLC + 1] = s;
    }
    return;
  }

  // generic coalesced dot blocks (lane j consecutive in every B read)
  const float* ap; const float* bp; int bs = 64, outBase, cnt = 64, len = 256;
  if (b2 < 64)        { ap = ZQ + b2 * 256;              bp = ws + OFF_LKT;   outBase = OFF_AL + b2 * 64; }
  else if (b2 < 128)  { int k = b2 - 64;  ap = ZQ + k * 256;  bp = ws + OFF_CKT;   outBase = OFF_AC + k * 64; }
  else if (b2 < 192)  { int k = b2 - 128; ap = LV + k * 256;  bp = Mm;             outBase = OFF_LVM + k * 64; }
  else if (b2 < 256)  { int k = b2 - 192; ap = CV + k * 256;  bp = Mm;             outBase = OFF_CVM + k * 64; }
  else if (b2 < 304)  { int s = b2 - 256; ap = VAp + s * 256; bp = Mm;             outBase = OFF_VM + s * 64; }
  else if (b2 < 368)  { int k = b2 - 304; ap = ZQ + k * 256;  bp = ws + OFF_KALLT; bs = 48; outBase = OFF_R1 + k * 64; cnt = 48; }
  else                { int i = b2 - 368; ap = Gm + i * 64;   bp = Gm;             outBase = OFF_G2 + i * 64; len = 64; }

  const int j = t & 63, ks = t >> 6;
  const int sl = len >> 2;
  const float* app = ap + ks * sl;
  const float* bpp = bp + (ks * sl) * bs + j;
  float a0 = 0.f, a1 = 0.f, a2 = 0.f, a3 = 0.f;
  #pragma unroll 4
  for (int m = 0; m < sl; m += 4) {
    a0 += app[m] * bpp[m * bs];
    a1 += app[m + 1] * bpp[(m + 1) * bs];
    a2 += app[m + 2] * bpp[(m + 2) * bs];
    a3 += app[m + 3] * bpp[(m + 3) * bs];
  }
  red[t] = (a0 + a1) + (a2 + a3);
  __syncthreads();
  if (t < cnt) ws[outBase + t] = red[t] + red[64 + t] + red[128 + t] + red[192 + t];
}

// ===================== K2: 1024 main blocks + register-sigma block =====================
__global__ __launch_bounds__(256, 3)
void k2_main(const float* __restrict__ z, const float* __restrict__ rw,
             const float* __restrict__ az, const float* __restrict__ arw,
             const float* __restrict__ acz, const float* __restrict__ ctrl,
             const float* __restrict__ ecov, const float* __restrict__ fb,
             float* __restrict__ ws) {
  __shared__ __align__(16) float sm[SMEM_K2];
  const int t = threadIdx.x;
  const int wv = t >> 6, ln = t & 63;

  if (blockIdx.x == 1024) {
    // ---------- sigma in registers: lane j holds column j of symmetric H ----------
    {
      float tv = (t < 64) ? ws[OFF_G2 + t * 65] : 0.f;
      #pragma unroll
      for (int m = 32; m >= 1; m >>= 1) tv += __shfl_xor(tv, m, 64);
      if (t == 0) sm[SG_SC0] = (tv > 0.f) ? 1.f / tv : 1.f;
    }
    __syncthreads();
    float colA[64];
    {
      float s0 = sm[SG_SC0];
      #pragma unroll
      for (int k = 0; k < 64; ++k) colA[k] = ws[OFF_G2 + k * 64 + ln] * s0;
    }
    __syncthreads();
    for (int it = 0; it < SQUARINGS; ++it) {
      float cnew[16];
      #pragma unroll
      for (int r = 0; r < 16; ++r) {
        const int i = wv * 16 + r;     // wave-uniform row
        float a0 = 0.f, a1 = 0.f;
        #pragma unroll
        for (int k = 0; k < 64; k += 2) {
          a0 = fmaf(rlane(colA[k], i),     colA[k],     a0);
          a1 = fmaf(rlane(colA[k + 1], i), colA[k + 1], a1);
        }
        cnew[r] = a0 + a1;
      }
      float* buf = sm + ((it & 1) ? SG_BUF1 : SG_BUF0);
      #pragma unroll
      for (int r = 0; r < 16; ++r) buf[(wv * 16 + r) * 64 + ln] = cnew[r];
      float tp = 0.f;
      #pragma unroll
      for (int r = 0; r < 16; ++r) tp += rlane(cnew[r], wv * 16 + r);
      if (ln == 0) sm[SG_TR + (it & 1) * 4 + wv] = tp;
      __syncthreads();
      float tr = sm[SG_TR + (it & 1) * 4 + 0] + sm[SG_TR + (it & 1) * 4 + 1]
               + sm[SG_TR + (it & 1) * 4 + 2] + sm[SG_TR + (it & 1) * 4 + 3];
      float scl = (tr > 0.f) ? 1.f / tr : 1.f;
      #pragma unroll
      for (int k = 0; k < 64; ++k) colA[k] = buf[k * 64 + ln] * scl;
      // next iter writes the OTHER buffer -> one barrier per iter suffices
    }
    // max-norm column pick (all waves compute identically)
    float cn = 0.f;
    #pragma unroll
    for (int k = 0; k < 64; ++k) cn = fmaf(colA[k], colA[k], cn);
    float bv = cn; int bj = ln;
    #pragma unroll
    for (int m = 32; m >= 1; m >>= 1) {
      float ov = __shfl_xor(bv, m, 64);
      int   oj = __shfl_xor(bj, m, 64);
      if (ov > bv || (ov == bv && oj < bj)) { bv = ov; bj = oj; }
    }
    if (wv == 0 && ln == bj) {
      #pragma unroll
      for (int k = 0; k < 64; ++k) sm[SG_V + k] = colA[k];
    }
    __syncthreads();
    if (t < 64) {                 // Rayleigh vs fp32 G (symmetric -> column reads coalesced)
      float vv = sm[SG_V + ln];
      float y = 0.f;
      #pragma unroll
      for (int k = 0; k < 64; ++k) y = fmaf(ws[OFF_G + k * 64 + ln], rlane(vv, k), y);
      float num = vv * y, den = vv * vv;
      #pragma unroll
      for (int m = 32; m >= 1; m >>= 1) {
        num += __shfl_xor(num, m, 64);
        den += __shfl_xor(den, m, 64);
      }
      if (t == 0) {
        float lam = (den > 1e-37f) ? num / den : 0.f;
        lam = fmaxf(lam, 0.f);
        float sg = sqrtf(lam);
        ws[OFF_RS] = 1.f / fmaxf(sg, 1e-8f);
      }
    }
    return;
  }

  // ---- stage consts into LDS ----
  for (int e = t; e < 418; e += 256) {
    float v;
    if (e < 48)       v = ws[OFF_CS + e];
    else if (e < 96)  v = ws[OFF_AN2 + e - 48];
    else if (e < 160) v = ws[OFF_VL + e - 96];
    else if (e < 224) v = ws[OFF_VC + e - 160];
    else if (e < 288) v = ws[OFF_BVML + e - 224];
    else if (e < 352) v = ws[OFF_BVMC + e - 288];
    else if (e < 416) v = fb[e - 352];
    else              v = ws[OFF_CLC + e - 416];
    sm[e] = v;
  }

  // ---- folded weights into registers (k-slice 16 per wave, lane = output col) ----
  float aLr[16], aCr[16], lvr[16], cvr[16], rAr[16], rBr[16], vmr[12];
  {
    const int kb = wv << 4;
    #pragma unroll
    for (int kk = 0; kk < 16; ++kk) {
      const int k = kb + kk;
      aLr[kk] = ws[OFF_AL  + k * 64 + ln];
      aCr[kk] = ws[OFF_AC  + k * 64 + ln];
      lvr[kk] = ws[OFF_LVM + k * 64 + ln];
      cvr[kk] = ws[OFF_CVM + k * 64 + ln];
      rAr[kk] = ws[OFF_R1  + k * 64 + ln];
      rBr[kk] = ws[OFF_R2  + k * 64 + ln];
    }
    #pragma unroll
    for (int ss = 0; ss < 12; ++ss) vmr[ss] = ws[OFF_VM + (wv * 12 + ss) * 64 + ln];
  }

  const int b0 = blockIdx.x * 4;

  // ---- phase 1: bilinear partials ----
  #pragma unroll
  for (int bi = 0; bi < 4; ++bi) {
    const int gb = b0 + bi;
    const float vz = z[gb * 64 + ln];
    const float va = az[gb * 64 + ln];
    const float vq = acz[gb * 64 + ln];
    float t1 = 0.f, t2 = 0.f, t3 = 0.f, t4 = 0.f, r1 = 0.f, r2 = 0.f;
    #pragma unroll
    for (int kk = 0; kk < 16; ++kk) {
      const int ksrc = (wv << 4) + kk;
      float sz = rlane(vz, ksrc);
      float sa = rlane(va, ksrc);
      float sq = rlane(vq, ksrc);
      t1 = fmaf(sz, aLr[kk], t1);
      t2 = fmaf(sz, aCr[kk], t2);
      r1 = fmaf(sz, rAr[kk], r1);
      r2 = fmaf(sz, rBr[kk], r2);
      t3 = fmaf(sa, lvr[kk], t3);
      t4 = fmaf(sq, cvr[kk], t4);
    }
    const int pb = S_PART + ((bi * 6) * 4 + wv) * 64 + ln;
    sm[pb]        = t1;
    sm[pb + 256]  = t2;
    sm[pb + 512]  = t3;
    sm[pb + 768]  = t4;
    sm[pb + 1024] = r1;
    sm[pb + 1280] = r2;
    if (bi == wv) {
      float zn = vz * vz;
      float dl = (vz - va) * (vz - va);
      float dq = (vz - vq) * (vz - vq);
      #pragma unroll
      for (int m = 32; m >= 1; m >>= 1) {
        zn += __shfl_xor(zn, m, 64);
        dl += __shfl_xor(dl, m, 64);
        dq += __shfl_xor(dq, m, 64);
      }
      if (ln == 0) {
        sm[S_SCL + bi * 16 + 2] = zn;
        sm[S_SCL + bi * 16 + 3] = dl;
        sm[S_SCL + bi * 16 + 4] = dq;
      }
    }
  }
  __syncthreads();

  // ---- phase 2: cross-wave reduce ----
  for (int tid = wv; tid < 24; tid += 4) {
    const int b = tid / 6, v = tid % 6;
    const int pb = S_PART + ((b * 6 + v) * 4) * 64 + ln;
    float s0 = sm[pb] + sm[pb + 64] + sm[pb + 128] + sm[pb + 192];
    if (v < 2) {
      const float xv = (v == 0) ? az[(b0 + b) * 64 + ln] : acz[(b0 + b) * 64 + ln];
      float d1 = s0 * xv;
      float d2 = xv * sm[((v == 0) ? C_VL : C_VC) + ln];
      #pragma unroll
      for (int m = 32; m >= 1; m >>= 1) {
        d1 += __shfl_xor(d1, m, 64);
        d2 += __shfl_xor(d2, m, 64);
      }
      if (ln == 0) {
        sm[S_SCL + b * 16 + v]     = d1;
        sm[S_SCL + b * 16 + 5 + v] = d2;
      }
    } else {
      sm[S_REDV + (b * 4 + (v - 2)) * 64 + ln] = s0;
    }
  }
  __syncthreads();

  // ---- phase 3: scores + softmax (wave wv -> batch wv) ----
  {
    const int b = wv, gb = b0 + b;
    float rwv = 1.f;
    if (ln < 16)      rwv = arw[gb * 16 + ln];
    else if (ln < 48) rwv = rw[gb * 32 + (ln - 16)];
    float sc_;
    if (ln < 48) {
      float qk = sm[S_REDV + (b * 4 + 2) * 64 + ln] + sm[C_CS + ln];
      float za = (ln < 16) ? sm[S_REDV + (b * 4 + 2) * 64 + 48 + ln]
                           : sm[S_REDV + (b * 4 + 3) * 64 + (ln - 16)];
      float d2 = sm[S_SCL + b * 16 + 2] - 2.f * za + sm[C_AN2 + ln];
      sc_ = rwv * qk * 0.0625f - d2;
    } else if (ln == 48) {
      sc_ = (sm[S_SCL + b * 16 + 0] + sm[S_REDV + (b * 4 + 3) * 64 + 32]
             + sm[S_SCL + b * 16 + 5] + sm[C_CLC]) * 0.0625f - sm[S_SCL + b * 16 + 3];
    } else if (ln == 49) {
      sc_ = (sm[S_SCL + b * 16 + 1] + sm[S_REDV + (b * 4 + 3) * 64 + 33]
             + sm[S_SCL + b * 16 + 6] + sm[C_CLC + 1]) * 0.0625f - sm[S_SCL + b * 16 + 4];
    } else sc_ = -3.0e30f;
    float mx = sc_;
    #pragma unroll
    for (int m = 32; m >= 1; m >>= 1) mx = fmaxf(mx, __shfl_xor(mx, m, 64));
    float ex = (ln < 50) ? __expf(sc_ - mx) : 0.f;
    float sum = ex;
    #pragma unroll
    for (int m = 32; m >= 1; m >>= 1) sum += __shfl_xor(sum, m, 64);
    float wgt = ex / sum;
    if (ln < 48)       sm[S_WSW + b * 48 + ln] = wgt * rwv;
    else if (ln == 48) sm[S_SCL + b * 16 + 7] = wgt;
    else if (ln == 49) sm[S_SCL + b * 16 + 8] = wgt;
  }
  __syncthreads();

  // ---- phase 4: VM partial ----
  #pragma unroll
  for (int bi = 0; bi < 4; ++bi) {
    float gp = 0.f;
    #pragma unroll
    for (int ss = 0; ss < 12; ++ss)
      gp = fmaf(sm[S_WSW + bi * 48 + wv * 12 + ss], vmr[ss], gp);
    sm[S_GP + (bi * 4 + wv) * 64 + ln] = gp;
  }
  __syncthreads();

  // ---- phase 5: assemble g, projection epilogue ----
  {
    const int b = wv, gb = b0 + b;
    const int gp0 = S_GP + (b * 4) * 64 + ln;
    float g = sm[gp0] + sm[gp0 + 64] + sm[gp0 + 128] + sm[gp0 + 192];
    float wL = sm[S_SCL + b * 16 + 7], wC = sm[S_SCL + b * 16 + 8];
    g = fmaf(wL, sm[S_REDV + (b * 4 + 0) * 64 + ln] + sm[C_BVML + ln], g);
    g = fmaf(wC, sm[S_REDV + (b * 4 + 1) * 64 + ln] + sm[C_BVMC + ln], g);
    float c = ctrl[gb * 64 + ln];
    float e = ecov[gb * 64 + ln];
    float fbv = sm[C_FB + ln];
    float gc = g * c, ge = g * e, ec = e * c, ee = e * e, fc = fbv * c, fe = fbv * e;
    #pragma unroll
    for (int m = 32; m >= 1; m >>= 1) {
      gc += __shfl_xor(gc, m, 64);
      ge += __shfl_xor(ge, m, 64);
      ec += __shfl_xor(ec, m, 64);
      ee += __shfl_xor(ee, m, 64);
      fc += __shfl_xor(fc, m, 64);
      fe += __shfl_xor(fe, m, 64);
    }
    if (ln == 0) {
      float A, Bv;
      if (ee > 1e-8f) { float r = ec / ee; A = gc - ge * r; Bv = fc - fe * r; }
      else { A = gc; Bv = fc; }
      ws[OFF_A  + gb] = A;
      ws[OFF_Bc + gb] = Bv;
    }
  }
}

// ===================== K3: apply 1/sigma =====================
__global__ __launch_bounds__(256)
void k3_out(const float* __restrict__ ws, float* __restrict__ out) {
  int b = blockIdx.x * 256 + threadIdx.x;
  float rs = ws[OFF_RS];
  out[b] = fmaf(ws[OFF_A + b], rs, ws[OFF_Bc + b]);
}

extern "C" void kernel_launch(void* const* d_in, const int* in_sizes, int n_in,
                              void* d_out, int out_size, void* d_ws, size_t ws_size,
                              hipStream_t stream) {
  const float* z     = (const float*)d_in[0];
  const float* rw    = (const float*)d_in[1];
  const float* az    = (const float*)d_in[2];
  const float* arw   = (const float*)d_in[3];
  const float* acz   = (const float*)d_in[4];
  const float* ctrl  = (const float*)d_in[5];
  const float* ecov  = (const float*)d_in[6];
  const float* chemb = (const float*)d_in[7];
  const float* chanc = (const float*)d_in[8];
  const float* aemb  = (const float*)d_in[9];
  const float* aanc  = (const float*)d_in[10];
  const float* zW    = (const float*)d_in[11];
  const float* zb    = (const float*)d_in[12];
  const float* latW  = (const float*)d_in[13];
  const float* latb  = (const float*)d_in[14];
  const float* codeW = (const float*)d_in[15];
  const float* codeb = (const float*)d_in[16];
  const float* Wq    = (const float*)d_in[17];
  const float* Wk    = (const float*)d_in[18];
  const float* Wv    = (const float*)d_in[19];
  const float* Wo    = (const float*)d_in[20];
  const float* fW    = (const float*)d_in[21];
  const float* fb    = (const float*)d_in[22];
  float* ws  = (float*)d_ws;
  float* out = (float*)d_out;

  k1a_fold<<<2004, 256, 0, stream>>>(chemb, aemb, zW, zb, latW, latb, codeW, codeb,
                                     Wq, Wk, Wv, Wo, fW, ws);
  k1b_fold<<<434, 256, 0, stream>>>(chanc, aanc, ws);
  k2_main<<<1025, 256, 0, stream>>>(z, rw, az, arw, acz, ctrl, ecov, fb, ws);
  k3_out<<<16, 256, 0, stream>>>(ws, out);
}